// Round 4
// baseline (448.050 us; speedup 1.0000x reference)
//
#include <hip/hip_runtime.h>
#include <hip/hip_bf16.h>
#include <stdint.h>

#define IN_F 4096
#define OUT_F 11008
#define TOKENS 32
#define NELEM_W (OUT_F * IN_F)        // 45088768 weights, ~180 MB fp32
#define OUT_ELEMS (TOKENS * OUT_F)    // 352256

typedef __attribute__((ext_vector_type(8))) __bf16 bf16x8;
typedef __attribute__((ext_vector_type(4))) float  f32x4;

// d_ws layout (bytes):
//   [0, 64):     scalars: f[0]=sampled |w| sum (atomic), u[1]=exc_count,
//                         f[4]=exact thr, f[5]=exact scale
//   [64,+256K):  xb — x converted to bf16
//   [262208):    apart — 2048 per-detect-block sum(|w|) partials
//   [270400):    gpart — 2 x 352256 f32 split-K partials (fixup patches half 0)
//   [3088448):   exception buffer: uint32 global float4 index, 4 MB
#define XB_OFF    64
#define APART_OFF 262208
#define GPART_OFF 270400
#define EXC_OFF   3088448
#define EXC_CAP   1048576u

#define N_SAMPLE_F 1048576.0f   // sample kernel reads exactly 2^20 weights
#define DELTA 0.004f            // band half-width ~5.4 sigma of th_hat error
#define DET_BLOCKS 2048

// fp32 -> bf16 bits (round-to-nearest-even), result in low 16
__device__ __forceinline__ uint32_t bfr(float v) {
    uint32_t u = __float_as_uint(v);
    uint32_t r = u + 0x7FFFu + ((u >> 16) & 1u);
    return r >> 16;
}

// provisional threshold from the single stored sampled sum wsf[0] —
// deterministic function of one stored float => identical in every consumer.
__device__ __forceinline__ float thr_hat_from(float ssum) {
    float m = ssum * (1.0f / N_SAMPLE_F);
    if (m < 1e-5f) m = 1e-5f;
    return 0.7f * m;
}

// ---------------- pass 0: sampled |w| sum + x->bf16 ----------------
// Blocks 0..255 sample 2^20 weights (coalesced float4 stripes), atomicAdd
// into wsf[0] (zeroed by hipMemsetAsync before this dispatch).
// Blocks 256..319: x conversion (16384 threads, 8 floats each).
__global__ __launch_bounds__(256) void sample_xcvt_kernel(const float* __restrict__ w,
                                                          const float* __restrict__ x,
                                                          float* __restrict__ wsf,
                                                          uint4* __restrict__ xb) {
    if (blockIdx.x >= 256) {
        int i = (blockIdx.x - 256) * 256 + threadIdx.x;
        const float4* x4 = (const float4*)x;
        float4 a0 = x4[i * 2];
        float4 a1 = x4[i * 2 + 1];
        uint4 o;
        o.x = bfr(a0.x) | (bfr(a0.y) << 16);
        o.y = bfr(a0.z) | (bfr(a0.w) << 16);
        o.z = bfr(a1.x) | (bfr(a1.y) << 16);
        o.w = bfr(a1.z) | (bfr(a1.w) << 16);
        xb[i] = o;
        return;
    }
    const int wv   = threadIdx.x >> 6;
    const int lane = threadIdx.x & 63;
    const int wid  = blockIdx.x * 4 + wv;
    const float4* w4 = (const float4*)w;
    size_t base = (size_t)wid * 11008 + lane;
    float s = 0.f;
#pragma unroll
    for (int r = 0; r < 4; ++r) {
        float4 v = w4[base + (size_t)r * 2752];
        s += __builtin_fabsf(v.x) + __builtin_fabsf(v.y) +
             __builtin_fabsf(v.z) + __builtin_fabsf(v.w);
    }
    for (int off = 32; off > 0; off >>= 1) s += __shfl_down(s, off, 64);
    __shared__ float ws4[4];
    if (lane == 0) ws4[wv] = s;
    __syncthreads();
    if (threadIdx.x == 0) atomicAdd(&wsf[0], ws4[0] + ws4[1] + ws4[2] + ws4[3]);
}

// ---------------- ternarize helpers ----------------
__device__ __forceinline__ uint32_t tern1(float v, float thr) {
    uint32_t u  = __float_as_uint(v);
    uint32_t pm = (u & 0x80000000u) | 0x3F800000u;   // +-1.0f
    return (__builtin_fabsf(v) > thr) ? pm : 0u;
}

// 4 fp32 -> 4 ternary bf16 packed in uint2 (v_perm for the pack)
__device__ __forceinline__ uint2 tern4(float4 b, float thr) {
    uint32_t q0 = tern1(b.x, thr), q1 = tern1(b.y, thr);
    uint32_t q2 = tern1(b.z, thr), q3 = tern1(b.w, thr);
    uint2 r;
    r.x = __builtin_amdgcn_perm(q1, q0, 0x07060302u);   // lo16=q0.hi16, hi16=q1.hi16
    r.y = __builtin_amdgcn_perm(q3, q2, 0x07060302u);
    return r;
}

// ---------------- pass 1: LDS-staged ternary GEMM — round-0 body VERBATIM -----
// Grid: 688 o-groups x 2 K-halves = 1376 blocks of 128 (2 waves), all resident.
// ONLY delta vs the proven 279-us kernel: thr computed from wsf[0] (3 scalar
// ops pre-loop) instead of loaded from wsf[2]. NOTHING added to the loop.
#define CHUNKS 16
#define WAVE_LDS 2304          // 16 rows * 144 B
#define SMEM_BYTES 4608        // 2 waves; also covers 2*512*4 reduce buf

__global__ __launch_bounds__(128, 4) void ternary_gemm(const float* __restrict__ w,
                                                       const float* __restrict__ wsf,
                                                       const __bf16* __restrict__ xb,
                                                       float* __restrict__ gpart) {
    __shared__ char smem_raw[SMEM_BYTES];
    const float thr = thr_hat_from(wsf[0]);   // provisional threshold
    const int og   = blockIdx.x >> 1;
    const int kh   = blockIdx.x & 1;
    const int tid  = threadIdx.x;
    const int wv   = tid >> 6;
    const int lane = tid & 63;
    const int col  = lane & 15;     // fragment: output col in group / token
    const int quad = lane >> 4;     // fragment k sub-block; staging row group
    const int rlan = lane & 15;     // staging: 16-B slot within a row

    const int kw = kh * 2048 + wv * 1024;

    const float* wp = w + (size_t)(og * 16 + quad) * IN_F + kw + rlan * 4;
    char* stage = smem_raw + wv * WAVE_LDS;
    char* wr    = stage + quad * 144 + rlan * 8;   // + j*576 per staging instr
    const char* rd = stage + col * 144;
    const __bf16* xq = xb + (size_t)col * IN_F + kw + quad * 8;

    f32x4 acc0 = {0.f, 0.f, 0.f, 0.f};
    f32x4 acc1 = {0.f, 0.f, 0.f, 0.f};

    float4 wb[2][4];
    bf16x8 xv[2][4];

#pragma unroll
    for (int c = 0; c < 2; ++c) {
        const float*  np = wp + c * 64;
        const __bf16* xn = xq + c * 64;
        wb[c][0] = *(const float4*)(np);
        wb[c][1] = *(const float4*)(np + 4 * IN_F);
        wb[c][2] = *(const float4*)(np + 8 * IN_F);
        wb[c][3] = *(const float4*)(np + 12 * IN_F);
        xv[c][0] = *(const bf16x8*)(xn);
        xv[c][1] = *(const bf16x8*)(xn + 32);
        xv[c][2] = *(const bf16x8*)(xn + 16 * IN_F);
        xv[c][3] = *(const bf16x8*)(xn + 16 * IN_F + 32);
    }

#define GEMM_BODY(c, cur)                                                      \
    {                                                                          \
        uint2 t0 = tern4(wb[cur][0], thr);                                     \
        uint2 t1 = tern4(wb[cur][1], thr);                                     \
        uint2 t2 = tern4(wb[cur][2], thr);                                     \
        uint2 t3 = tern4(wb[cur][3], thr);                                     \
        *(uint2*)(wr)        = t0;                                             \
        *(uint2*)(wr + 576)  = t1;                                             \
        *(uint2*)(wr + 1152) = t2;                                             \
        *(uint2*)(wr + 1728) = t3;                                             \
        bf16x8 a00 = xv[cur][0], a01 = xv[cur][1];                             \
        bf16x8 a10 = xv[cur][2], a11 = xv[cur][3];                             \
        if ((c) + 2 < CHUNKS) {                                                \
            const float*  np = wp + ((c) + 2) * 64;                            \
            const __bf16* xn = xq + ((c) + 2) * 64;                            \
            wb[cur][0] = *(const float4*)(np);                                 \
            wb[cur][1] = *(const float4*)(np + 4 * IN_F);                      \
            wb[cur][2] = *(const float4*)(np + 8 * IN_F);                      \
            wb[cur][3] = *(const float4*)(np + 12 * IN_F);                     \
            xv[cur][0] = *(const bf16x8*)(xn);                                 \
            xv[cur][1] = *(const bf16x8*)(xn + 32);                            \
            xv[cur][2] = *(const bf16x8*)(xn + 16 * IN_F);                     \
            xv[cur][3] = *(const bf16x8*)(xn + 16 * IN_F + 32);                \
        }                                                                      \
        bf16x8 bw0 = *(const bf16x8*)(rd + quad * 16);                         \
        bf16x8 bw1 = *(const bf16x8*)(rd + 64 + quad * 16);                    \
        acc0 = __builtin_amdgcn_mfma_f32_16x16x32_bf16(a00, bw0, acc0, 0, 0, 0); \
        acc1 = __builtin_amdgcn_mfma_f32_16x16x32_bf16(a10, bw0, acc1, 0, 0, 0); \
        acc0 = __builtin_amdgcn_mfma_f32_16x16x32_bf16(a01, bw1, acc0, 0, 0, 0); \
        acc1 = __builtin_amdgcn_mfma_f32_16x16x32_bf16(a11, bw1, acc1, 0, 0, 0); \
    }

    for (int c = 0; c < CHUNKS; c += 2) {
        GEMM_BODY(c, 0)
        GEMM_BODY(c + 1, 1)
    }
#undef GEMM_BODY

    __syncthreads();
    float* red  = (float*)smem_raw;
    float* base = red + wv * 512;
#pragma unroll
    for (int r = 0; r < 4; ++r) base[r * 64 + lane]       = acc0[r];
#pragma unroll
    for (int r = 0; r < 4; ++r) base[256 + r * 64 + lane] = acc1[r];
    __syncthreads();

    // 512 outputs (32 tokens x 16 cols), 4 per thread, summed over 2 waves
    float* gp = gpart + (size_t)kh * OUT_ELEMS;
    for (int p = tid; p < 512; p += 128) {
        int t = p >> 4, cc = p & 15;
        int a = t >> 4;
        int q = (t >> 2) & 3;
        int r = t & 3;
        int idx = a * 256 + r * 64 + q * 16 + cc;
        gp[(size_t)t * OUT_F + og * 16 + cc] = red[idx] + red[512 + idx];
    }
}

// ---------------- pass 2: exact |w| partials + band detection (streaming) -----
// Round-0 absum shape (2048x256 grid-stride, proven ~6 TB/s). Runs right after
// the gemm -> large fraction of w is L3-resident. Band hits appended to an LDS
// buffer (expected ~67/block), flushed with ONE global atomic per block.
__global__ __launch_bounds__(256) void absum_detect(const float* __restrict__ w,
                                                    const float* __restrict__ wsf,
                                                    float* __restrict__ apart,
                                                    unsigned int* __restrict__ excg,
                                                    unsigned int* __restrict__ exc_cnt) {
    __shared__ unsigned int ebuf[512];
    __shared__ unsigned int en;
    __shared__ unsigned int ebase;
    __shared__ float wsum[4];
    if (threadIdx.x == 0) en = 0u;
    __syncthreads();

    const float th  = thr_hat_from(wsf[0]);
    const float eps = th * DELTA;

    int tid = blockIdx.x * blockDim.x + threadIdx.x;
    int stride = DET_BLOCKS * 256;
    const float4* w4 = (const float4*)w;
    const int n4 = NELEM_W / 4;
    float s = 0.f;
    for (int i = tid; i < n4; i += stride) {
        float4 v = w4[i];
        float ax = __builtin_fabsf(v.x), ay = __builtin_fabsf(v.y);
        float az = __builtin_fabsf(v.z), aw = __builtin_fabsf(v.w);
        s += ax + ay + az + aw;
        int h = (__builtin_fabsf(ax - th) < eps) | (__builtin_fabsf(ay - th) < eps) |
                (__builtin_fabsf(az - th) < eps) | (__builtin_fabsf(aw - th) < eps);
        if (h) {
            unsigned int p = atomicAdd(&en, 1u);
            if (p < 512u) ebuf[p] = (unsigned int)i;   // global float4 index
        }
    }
    for (int off = 32; off > 0; off >>= 1) s += __shfl_down(s, off, 64);
    int lane = threadIdx.x & 63;
    int wv   = threadIdx.x >> 6;
    if (lane == 0) wsum[wv] = s;
    __syncthreads();
    if (threadIdx.x == 0) {
        apart[blockIdx.x] = wsum[0] + wsum[1] + wsum[2] + wsum[3];
        unsigned int n = en > 512u ? 512u : en;
        ebase = atomicAdd(exc_cnt, n);
    }
    __syncthreads();
    unsigned int n = en > 512u ? 512u : en;
    unsigned int gb = ebase;
    for (unsigned int e = threadIdx.x; e < n; e += 256) {
        unsigned int g = gb + e;
        if (g < EXC_CAP) excg[g] = ebuf[e];
    }
}

// ---------------- pass 3: reduce 2048 partials -> exact thr/scale ----------------
__global__ __launch_bounds__(256) void finalize_kernel(const float* __restrict__ apart,
                                                       float* __restrict__ wsf) {
    float s = 0.f;
#pragma unroll
    for (int j = 0; j < 8; ++j)
        s += apart[threadIdx.x + 256 * j];
    for (int off = 32; off > 0; off >>= 1) s += __shfl_down(s, off, 64);
    __shared__ float wsum[4];
    int lane = threadIdx.x & 63;
    int wv   = threadIdx.x >> 6;
    if (lane == 0) wsum[wv] = s;
    __syncthreads();
    if (threadIdx.x == 0) {
        double mean = (double)(wsum[0] + wsum[1] + wsum[2] + wsum[3]) / (double)NELEM_W;
        if (mean < 1e-5) mean = 1e-5;
        float mf = (float)mean;
        wsf[4] = 0.7f * mf;   // exact threshold
        wsf[5] = mf;          // exact scale
    }
}

// ---------------- pass 4: exception fixup (patch unscaled gpart half 0) --------
__global__ __launch_bounds__(128) void fixup_kernel(const unsigned int* __restrict__ excg,
                                                    const float* __restrict__ w,
                                                    const float* __restrict__ wsf,
                                                    const unsigned int* __restrict__ exc_cnt,
                                                    const __bf16* __restrict__ xb,
                                                    float* __restrict__ gpart) {
    const float th  = thr_hat_from(wsf[0]);   // decision the gemm used
    const float thr = wsf[4];                 // exact decision
    unsigned int n = *exc_cnt;
    if (n > EXC_CAP) n = EXC_CAP;
    const float4* w4 = (const float4*)w;
    for (unsigned int g = blockIdx.x * 128 + threadIdx.x; g < n; g += gridDim.x * 128) {
        unsigned int idx4 = excg[g];
        float4 v4 = w4[idx4];
        unsigned int o     = idx4 >> 10;          // row (IN_F/4 = 1024)
        unsigned int ibase = (idx4 & 1023u) * 4u; // column of element 0
        float el[4] = {v4.x, v4.y, v4.z, v4.w};
#pragma unroll
        for (int e = 0; e < 4; ++e) {
            float v = el[e];
            float a = __builtin_fabsf(v);
            bool qt = a > thr;
            bool qh = a > th;
            if (qt != qh) {
                float sgn = (__float_as_uint(v) & 0x80000000u) ? -1.0f : 1.0f;
                float d   = qt ? sgn : -sgn;
                const __bf16* xp = xb + (ibase + e);
                for (int t = 0; t < TOKENS; ++t)
                    atomicAdd(&gpart[(size_t)t * OUT_F + o], d * (float)xp[(size_t)t * IN_F]);
            }
        }
    }
}

// ---------------- pass 5: combine split-K halves + exact scale ----------------
__global__ __launch_bounds__(256) void combine_kernel(const float* __restrict__ gpart,
                                                      const float* __restrict__ wsf,
                                                      float* __restrict__ out) {
    const float sc = wsf[5];
    int i = blockIdx.x * 256 + threadIdx.x;   // float4 index, 88064 total
    const float4* p0 = (const float4*)gpart;
    const float4* p1 = (const float4*)(gpart + OUT_ELEMS);
    float4 a = p0[i], b = p1[i];
    float4 o;
    o.x = (a.x + b.x) * sc;
    o.y = (a.y + b.y) * sc;
    o.z = (a.z + b.z) * sc;
    o.w = (a.w + b.w) * sc;
    ((float4*)out)[i] = o;
}

extern "C" void kernel_launch(void* const* d_in, const int* in_sizes, int n_in,
                              void* d_out, int out_size, void* d_ws, size_t ws_size,
                              hipStream_t stream) {
    const float* x = (const float*)d_in[0];   // [32, 4096]
    const float* w = (const float*)d_in[1];   // [11008, 4096]
    float* out     = (float*)d_out;           // [32, 11008]
    char* ws       = (char*)d_ws;

    float*        wsf   = (float*)ws;
    unsigned int* wsu   = (unsigned int*)ws;
    uint4*        xb    = (uint4*)(ws + XB_OFF);
    float*        apart = (float*)(ws + APART_OFF);
    float*        gpart = (float*)(ws + GPART_OFF);
    unsigned int* excg  = (unsigned int*)(ws + EXC_OFF);

    hipMemsetAsync(ws, 0, 64, stream);   // zero sampled sum + exception counter
    sample_xcvt_kernel<<<320, 256, 0, stream>>>(w, x, wsf, xb);
    ternary_gemm<<<1376, 128, 0, stream>>>(w, wsf, (const __bf16*)(ws + XB_OFF), gpart);
    absum_detect<<<DET_BLOCKS, 256, 0, stream>>>(w, wsf, apart, excg, wsu + 1);
    finalize_kernel<<<1, 256, 0, stream>>>(apart, wsf);
    fixup_kernel<<<512, 128, 0, stream>>>(excg, w, wsf, wsu + 1,
                                          (const __bf16*)(ws + XB_OFF), gpart);
    combine_kernel<<<344, 256, 0, stream>>>(gpart, wsf, out);
}

// Round 6
// 317.859 us; speedup vs baseline: 1.4096x; 1.4096x over previous
//
#include <hip/hip_runtime.h>
#include <hip/hip_bf16.h>
#include <stdint.h>

#define IN_F 4096
#define OUT_F 11008
#define TOKENS 32
#define NELEM_W (OUT_F * IN_F)        // 45088768 weights, ~180 MB fp32
#define OUT_ELEMS (TOKENS * OUT_F)    // 352256

typedef __attribute__((ext_vector_type(8))) __bf16 bf16x8;
typedef __attribute__((ext_vector_type(4))) float  f32x4;

// d_ws layout (bytes):
//   [0, 64):     scalars: f[0]=sampled |w| sum (atomic), u[1]=exc_count,
//                         f[4]=exact thr, f[5]=exact scale
//   [64,+256K):  xb — x converted to bf16 (row-major [32][4096])
//   [262208):    apart — 2048 per-detect-block sum(|w|) partials
//   [270400):    gpartT — 2 x [11008][32] f32 split-K partials, TOKEN-MINOR
//   [3088448):   exception buffer: uint32 global float4 index, 4 MB
#define XB_OFF    64
#define APART_OFF 262208
#define GPART_OFF 270400
#define EXC_OFF   3088448
#define EXC_CAP   1048576u

#define N_SAMPLE_F 1048576.0f   // sample kernel reads exactly 2^20 weights
#define DELTA 0.004f            // band half-width ~5.4 sigma of th_hat error
#define GEMM_BLOCKS 1376
#define DET_BLOCKS  2048

// fp32 -> bf16 bits (round-to-nearest-even), result in low 16
__device__ __forceinline__ uint32_t bfr(float v) {
    uint32_t u = __float_as_uint(v);
    uint32_t r = u + 0x7FFFu + ((u >> 16) & 1u);
    return r >> 16;
}

// provisional threshold from the single stored sampled sum wsf[0] —
// deterministic function of one stored float => identical in every consumer.
__device__ __forceinline__ float thr_hat_from(float ssum) {
    float m = ssum * (1.0f / N_SAMPLE_F);
    if (m < 1e-5f) m = 1e-5f;
    return 0.7f * m;
}

// ---------------- pass 0: sampled |w| sum + x->bf16 ----------------
__global__ __launch_bounds__(256) void sample_xcvt_kernel(const float* __restrict__ w,
                                                          const float* __restrict__ x,
                                                          float* __restrict__ wsf,
                                                          uint4* __restrict__ xb) {
    if (blockIdx.x >= 256) {
        int i = (blockIdx.x - 256) * 256 + threadIdx.x;
        const float4* x4 = (const float4*)x;
        float4 a0 = x4[i * 2];
        float4 a1 = x4[i * 2 + 1];
        uint4 o;
        o.x = bfr(a0.x) | (bfr(a0.y) << 16);
        o.y = bfr(a0.z) | (bfr(a0.w) << 16);
        o.z = bfr(a1.x) | (bfr(a1.y) << 16);
        o.w = bfr(a1.z) | (bfr(a1.w) << 16);
        xb[i] = o;
        return;
    }
    const int wv   = threadIdx.x >> 6;
    const int lane = threadIdx.x & 63;
    const int wid  = blockIdx.x * 4 + wv;
    const float4* w4 = (const float4*)w;
    size_t base = (size_t)wid * 11008 + lane;
    float s = 0.f;
#pragma unroll
    for (int r = 0; r < 4; ++r) {
        float4 v = w4[base + (size_t)r * 2752];
        s += __builtin_fabsf(v.x) + __builtin_fabsf(v.y) +
             __builtin_fabsf(v.z) + __builtin_fabsf(v.w);
    }
    for (int off = 32; off > 0; off >>= 1) s += __shfl_down(s, off, 64);
    __shared__ float ws4[4];
    if (lane == 0) ws4[wv] = s;
    __syncthreads();
    if (threadIdx.x == 0) atomicAdd(&wsf[0], ws4[0] + ws4[1] + ws4[2] + ws4[3]);
}

// ---------------- ternarize helpers ----------------
__device__ __forceinline__ uint32_t tern1(float v, float thr) {
    uint32_t u  = __float_as_uint(v);
    uint32_t pm = (u & 0x80000000u) | 0x3F800000u;   // +-1.0f
    return (__builtin_fabsf(v) > thr) ? pm : 0u;
}

__device__ __forceinline__ uint2 tern4(float4 b, float thr) {
    uint32_t q0 = tern1(b.x, thr), q1 = tern1(b.y, thr);
    uint32_t q2 = tern1(b.z, thr), q3 = tern1(b.w, thr);
    uint2 r;
    r.x = __builtin_amdgcn_perm(q1, q0, 0x07060302u);   // lo16=q0.hi16, hi16=q1.hi16
    r.y = __builtin_amdgcn_perm(q3, q2, 0x07060302u);
    return r;
}

// ---------------- pass 1: FUSED gemm + detect (one dispatch, two block roles) --
// Blocks [0,1376): round-0 gemm body VERBATIM; only the epilogue store changed
// (token-minor gpartT layout, still one coalesced float4 per thread).
// Blocks [1376,3424): streaming exact-absum + band detect; trails the gemm's
// w stream through L3 -> mostly cache-served. Ballot-based append: one lane-0
// branch per wave-iteration, no per-lane atomics.
#define CHUNKS 16
#define WAVE_LDS 2304          // 16 rows * 144 B
#define SMEM_BYTES 4608        // 2 waves; also covers 2*512*4 reduce buf

__global__ __launch_bounds__(128, 4) void fused_gemm_detect(const float* __restrict__ w,
                                                            const float* __restrict__ wsf,
                                                            const __bf16* __restrict__ xb,
                                                            float* __restrict__ gpartT,
                                                            float* __restrict__ apart,
                                                            unsigned int* __restrict__ excg,
                                                            unsigned int* __restrict__ exc_cnt) {
    __shared__ char smem_raw[SMEM_BYTES];
    __shared__ unsigned int en, ebase;
    __shared__ float wsumd[2];

    const float thr = thr_hat_from(wsf[0]);   // provisional threshold

    if (blockIdx.x < GEMM_BLOCKS) {
        // ---------------- gemm role (round-0 body, untouched loop) ----------------
        const int og   = blockIdx.x >> 1;
        const int kh   = blockIdx.x & 1;
        const int tid  = threadIdx.x;
        const int wv   = tid >> 6;
        const int lane = tid & 63;
        const int col  = lane & 15;
        const int quad = lane >> 4;
        const int rlan = lane & 15;

        const int kw = kh * 2048 + wv * 1024;

        const float* wp = w + (size_t)(og * 16 + quad) * IN_F + kw + rlan * 4;
        char* stage = smem_raw + wv * WAVE_LDS;
        char* wr    = stage + quad * 144 + rlan * 8;
        const char* rd = stage + col * 144;
        const __bf16* xq = xb + (size_t)col * IN_F + kw + quad * 8;

        f32x4 acc0 = {0.f, 0.f, 0.f, 0.f};
        f32x4 acc1 = {0.f, 0.f, 0.f, 0.f};

        float4 wb[2][4];
        bf16x8 xv[2][4];

#pragma unroll
        for (int c = 0; c < 2; ++c) {
            const float*  np = wp + c * 64;
            const __bf16* xn = xq + c * 64;
            wb[c][0] = *(const float4*)(np);
            wb[c][1] = *(const float4*)(np + 4 * IN_F);
            wb[c][2] = *(const float4*)(np + 8 * IN_F);
            wb[c][3] = *(const float4*)(np + 12 * IN_F);
            xv[c][0] = *(const bf16x8*)(xn);
            xv[c][1] = *(const bf16x8*)(xn + 32);
            xv[c][2] = *(const bf16x8*)(xn + 16 * IN_F);
            xv[c][3] = *(const bf16x8*)(xn + 16 * IN_F + 32);
        }

#define GEMM_BODY(c, cur)                                                      \
    {                                                                          \
        uint2 t0 = tern4(wb[cur][0], thr);                                     \
        uint2 t1 = tern4(wb[cur][1], thr);                                     \
        uint2 t2 = tern4(wb[cur][2], thr);                                     \
        uint2 t3 = tern4(wb[cur][3], thr);                                     \
        *(uint2*)(wr)        = t0;                                             \
        *(uint2*)(wr + 576)  = t1;                                             \
        *(uint2*)(wr + 1152) = t2;                                             \
        *(uint2*)(wr + 1728) = t3;                                             \
        bf16x8 a00 = xv[cur][0], a01 = xv[cur][1];                             \
        bf16x8 a10 = xv[cur][2], a11 = xv[cur][3];                             \
        if ((c) + 2 < CHUNKS) {                                                \
            const float*  np = wp + ((c) + 2) * 64;                            \
            const __bf16* xn = xq + ((c) + 2) * 64;                            \
            wb[cur][0] = *(const float4*)(np);                                 \
            wb[cur][1] = *(const float4*)(np + 4 * IN_F);                      \
            wb[cur][2] = *(const float4*)(np + 8 * IN_F);                      \
            wb[cur][3] = *(const float4*)(np + 12 * IN_F);                     \
            xv[cur][0] = *(const bf16x8*)(xn);                                 \
            xv[cur][1] = *(const bf16x8*)(xn + 32);                            \
            xv[cur][2] = *(const bf16x8*)(xn + 16 * IN_F);                     \
            xv[cur][3] = *(const bf16x8*)(xn + 16 * IN_F + 32);                \
        }                                                                      \
        bf16x8 bw0 = *(const bf16x8*)(rd + quad * 16);                         \
        bf16x8 bw1 = *(const bf16x8*)(rd + 64 + quad * 16);                    \
        acc0 = __builtin_amdgcn_mfma_f32_16x16x32_bf16(a00, bw0, acc0, 0, 0, 0); \
        acc1 = __builtin_amdgcn_mfma_f32_16x16x32_bf16(a10, bw0, acc1, 0, 0, 0); \
        acc0 = __builtin_amdgcn_mfma_f32_16x16x32_bf16(a01, bw1, acc0, 0, 0, 0); \
        acc1 = __builtin_amdgcn_mfma_f32_16x16x32_bf16(a11, bw1, acc1, 0, 0, 0); \
    }

        for (int c = 0; c < CHUNKS; c += 2) {
            GEMM_BODY(c, 0)
            GEMM_BODY(c + 1, 1)
        }
#undef GEMM_BODY

        __syncthreads();
        float* red  = (float*)smem_raw;
        float* base = red + wv * 512;
#pragma unroll
        for (int r = 0; r < 4; ++r) base[r * 64 + lane]       = acc0[r];
#pragma unroll
        for (int r = 0; r < 4; ++r) base[256 + r * 64 + lane] = acc1[r];
        __syncthreads();

        // token-minor store: thread (cc,tq) writes float4 {t=4tq..4tq+3} for col cc
        float* gp = gpartT + (size_t)kh * OUT_ELEMS;
        int cc = tid & 15;
        int tq = tid >> 4;                       // 0..7
        int bi = (tq >> 2) * 256 + (tq & 3) * 16 + cc;
        f32x4 vo;
#pragma unroll
        for (int r = 0; r < 4; ++r) vo[r] = red[bi + r * 64] + red[512 + bi + r * 64];
        *(f32x4*)(gp + ((size_t)(og * 16 + cc) * 32 + tq * 4)) = vo;
    } else {
        // ---------------- detect role: exact |w| partials + band hits ----------------
        const int db   = blockIdx.x - GEMM_BLOCKS;   // 0..2047
        const int tid  = threadIdx.x;
        const int lane = tid & 63;
        const int wv   = tid >> 6;
        unsigned int* ebuf = (unsigned int*)smem_raw;   // 512 entries

        if (tid == 0) en = 0u;
        __syncthreads();

        const float eps = thr * DELTA;
        const float4* w4 = (const float4*)w;
        const unsigned n4 = (unsigned)(NELEM_W / 4);
        float s = 0.f;
        const unsigned tbase = (unsigned)db * 128u + (unsigned)tid;
        const unsigned wbase0 = (unsigned)db * 128u + (unsigned)wv * 64u;
        for (int k = 0; k < 43; ++k) {            // 2048*128*43 = 11272192 float4s
            unsigned i = tbase + (unsigned)k * 262144u;
            if (i >= n4) break;                   // provably never taken; defensive
            float4 v = w4[i];
            float ax = __builtin_fabsf(v.x), ay = __builtin_fabsf(v.y);
            float az = __builtin_fabsf(v.z), aw = __builtin_fabsf(v.w);
            s += ax + ay + az + aw;
            int h = (__builtin_fabsf(ax - thr) < eps) | (__builtin_fabsf(ay - thr) < eps) |
                    (__builtin_fabsf(az - thr) < eps) | (__builtin_fabsf(aw - thr) < eps);
            unsigned long long m = __ballot(h);
            if (lane == 0 && m) {
                unsigned c = (unsigned)__popcll(m);
                unsigned p = atomicAdd(&en, c);
                unsigned ib = wbase0 + (unsigned)k * 262144u;
                while (m) {
                    int b = __ffsll((unsigned long long)m) - 1;
                    m &= m - 1;
                    if (p < 512u) ebuf[p] = ib + (unsigned)b;
                    ++p;
                }
            }
        }
        for (int off = 32; off > 0; off >>= 1) s += __shfl_down(s, off, 64);
        if (lane == 0) wsumd[wv] = s;
        __syncthreads();
        if (tid == 0) {
            apart[db] = wsumd[0] + wsumd[1];
            unsigned n = en > 512u ? 512u : en;
            ebase = atomicAdd(exc_cnt, n);
        }
        __syncthreads();
        unsigned n = en > 512u ? 512u : en;
        unsigned gb = ebase;
        for (unsigned e = tid; e < n; e += 128) {
            unsigned g = gb + e;
            if (g < EXC_CAP) excg[g] = ebuf[e];
        }
    }
}

// ---------------- pass 2: reduce 2048 partials -> exact thr/scale ----------------
__global__ __launch_bounds__(256) void finalize_kernel(const float* __restrict__ apart,
                                                       float* __restrict__ wsf) {
    float s = 0.f;
#pragma unroll
    for (int j = 0; j < 8; ++j)
        s += apart[threadIdx.x + 256 * j];
    for (int off = 32; off > 0; off >>= 1) s += __shfl_down(s, off, 64);
    __shared__ float wsum[4];
    int lane = threadIdx.x & 63;
    int wv   = threadIdx.x >> 6;
    if (lane == 0) wsum[wv] = s;
    __syncthreads();
    if (threadIdx.x == 0) {
        double mean = (double)(wsum[0] + wsum[1] + wsum[2] + wsum[3]) / (double)NELEM_W;
        if (mean < 1e-5) mean = 1e-5;
        float mf = (float)mean;
        wsf[4] = 0.7f * mf;   // exact threshold
        wsf[5] = mf;          // exact scale
    }
}

// ---------------- pass 3: parallel fixup — half-wave per exception record ------
// lane = (record-pair select)*32 + token. Record's w-float4 load is one
// broadcast line; the 32 token updates are ONE coalesced 128-B atomic span in
// gpartT (token-minor). No serial token loop, no scattered write lines.
__global__ __launch_bounds__(256) void fixup_kernel(const unsigned int* __restrict__ excg,
                                                    const float* __restrict__ w,
                                                    const float* __restrict__ wsf,
                                                    const unsigned int* __restrict__ exc_cnt,
                                                    const __bf16* __restrict__ xb,
                                                    float* __restrict__ gpartT) {
    const float th  = thr_hat_from(wsf[0]);   // decision the gemm used
    const float thr = wsf[4];                 // exact decision
    unsigned n = *exc_cnt;
    if (n > EXC_CAP) n = EXC_CAP;
    const float4* w4 = (const float4*)w;
    const int lane = threadIdx.x & 63;
    const int sub  = lane >> 5;               // which record of the pair
    const int t    = lane & 31;               // token
    const unsigned gw = ((unsigned)blockIdx.x * 256u + (unsigned)threadIdx.x) >> 6;
    const unsigned nw = ((unsigned)gridDim.x * 256u) >> 6;
    for (unsigned g = gw * 2u + (unsigned)sub; g < n; g += nw * 2u) {
        unsigned idx4 = excg[g];
        float4 v4 = w4[idx4];                 // broadcast line within half-wave
        unsigned o     = idx4 >> 10;          // row (IN_F/4 = 1024)
        unsigned ibase = (idx4 & 1023u) * 4u; // column of element 0
        float upd = 0.f;
        float el[4] = {v4.x, v4.y, v4.z, v4.w};
#pragma unroll
        for (int e = 0; e < 4; ++e) {
            float v = el[e];
            float a = __builtin_fabsf(v);
            bool qt = a > thr;
            bool qh = a > th;
            if (qt != qh) {
                float sgn = (__float_as_uint(v) & 0x80000000u) ? -1.0f : 1.0f;
                float d   = qt ? sgn : -sgn;
                upd += d * (float)xb[(size_t)t * IN_F + ibase + (unsigned)e];
            }
        }
        if (upd != 0.f)
            atomicAdd(&gpartT[(size_t)o * 32u + (unsigned)t], upd);
    }
}

// ---------------- pass 4: combine split-K halves + exact scale (transpose) -----
// Block handles 128 o-values x 32 tokens: coalesced token-minor reads, LDS
// transpose (pad 33 to break bank conflicts), coalesced row-major writes.
__global__ __launch_bounds__(256) void combine_kernel(const float* __restrict__ gpartT,
                                                      const float* __restrict__ wsf,
                                                      float* __restrict__ out) {
    __shared__ float lt[128 * 33];
    const float sc = wsf[5];
    const int o0 = blockIdx.x * 128;
    const float4* g0 = (const float4*)(gpartT + (size_t)o0 * 32);
    const float4* g1 = (const float4*)(gpartT + OUT_ELEMS + (size_t)o0 * 32);
#pragma unroll
    for (int it = 0; it < 4; ++it) {
        int i4 = threadIdx.x + it * 256;      // float4 index within the tile
        float4 a = g0[i4], b = g1[i4];
        int pos = i4 * 4;
        int o = pos >> 5, t = pos & 31;
        float* dst = &lt[o * 33 + t];
        dst[0] = (a.x + b.x) * sc;
        dst[1] = (a.y + b.y) * sc;
        dst[2] = (a.z + b.z) * sc;
        dst[3] = (a.w + b.w) * sc;
    }
    __syncthreads();
    const int t  = threadIdx.x >> 3;          // 0..31
    const int oc = (threadIdx.x & 7) * 16;    // 0..112
    float* op = out + (size_t)t * OUT_F + o0 + oc;
#pragma unroll
    for (int m4 = 0; m4 < 4; ++m4) {
        float4 v;
        v.x = lt[(oc + m4 * 4 + 0) * 33 + t];
        v.y = lt[(oc + m4 * 4 + 1) * 33 + t];
        v.z = lt[(oc + m4 * 4 + 2) * 33 + t];
        v.w = lt[(oc + m4 * 4 + 3) * 33 + t];
        ((float4*)op)[m4] = v;
    }
}

extern "C" void kernel_launch(void* const* d_in, const int* in_sizes, int n_in,
                              void* d_out, int out_size, void* d_ws, size_t ws_size,
                              hipStream_t stream) {
    const float* x = (const float*)d_in[0];   // [32, 4096]
    const float* w = (const float*)d_in[1];   // [11008, 4096]
    float* out     = (float*)d_out;           // [32, 11008]
    char* ws       = (char*)d_ws;

    float*        wsf   = (float*)ws;
    unsigned int* wsu   = (unsigned int*)ws;
    uint4*        xb    = (uint4*)(ws + XB_OFF);
    float*        apart = (float*)(ws + APART_OFF);
    float*        gpartT= (float*)(ws + GPART_OFF);
    unsigned int* excg  = (unsigned int*)(ws + EXC_OFF);

    hipMemsetAsync(ws, 0, 64, stream);   // zero sampled sum + exception counter
    sample_xcvt_kernel<<<320, 256, 0, stream>>>(w, x, wsf, xb);
    fused_gemm_detect<<<GEMM_BLOCKS + DET_BLOCKS, 128, 0, stream>>>(
        w, wsf, (const __bf16*)(ws + XB_OFF), gpartT, apart, excg, wsu + 1);
    finalize_kernel<<<1, 256, 0, stream>>>(apart, wsf);
    fixup_kernel<<<2048, 256, 0, stream>>>(excg, w, wsf, wsu + 1,
                                           (const __bf16*)(ws + XB_OFF), gpartT);
    combine_kernel<<<OUT_F / 128, 256, 0, stream>>>(gpartT, wsf, out);
}

// Round 7
// 280.138 us; speedup vs baseline: 1.5994x; 1.1346x over previous
//
#include <hip/hip_runtime.h>
#include <hip/hip_bf16.h>
#include <stdint.h>

#define IN_F 4096
#define OUT_F 11008
#define TOKENS 32
#define NELEM_W (OUT_F * IN_F)   // 45088768 weights, ~180 MB fp32
#define OUT_ELEMS (TOKENS * OUT_F)   // 352256

typedef __attribute__((ext_vector_type(8))) __bf16 bf16x8;
typedef __attribute__((ext_vector_type(4))) float  f32x4;

// d_ws layout (bytes):
//   [0, 64):           scalars: f[2]=threshold, f[3]=scale
//   [64, 64+256K):     xb  — x converted to bf16
//   [262208, +2.8M):   gemm split-K partials: 2 x 352256 f32
//   [3080256, +8K):    absum per-block partials: 2048 f32
#define XB_OFF    64
#define GPART_OFF 262208
#define APART_OFF 3080256

// fp32 -> bf16 bits (round-to-nearest-even), result in low 16
__device__ __forceinline__ uint32_t bfr(float v) {
    uint32_t u = __float_as_uint(v);
    uint32_t r = u + 0x7FFFu + ((u >> 16) & 1u);
    return r >> 16;
}

// ---------------- pass 1: sum(|w|) partials + x->bf16 conversion ----------------
#define ABSUM_BLOCKS 2048
#define XCVT_BLOCKS  64

__global__ __launch_bounds__(256) void absum_xcvt_kernel(const float* __restrict__ w,
                                                         const float* __restrict__ x,
                                                         float* __restrict__ apart,
                                                         uint4* __restrict__ xb) {
    if (blockIdx.x >= ABSUM_BLOCKS) {
        // x conversion: 16384 threads, 8 floats each
        int i = (blockIdx.x - ABSUM_BLOCKS) * 256 + threadIdx.x;
        const float4* x4 = (const float4*)x;
        float4 a0 = x4[i * 2];
        float4 a1 = x4[i * 2 + 1];
        uint4 o;
        o.x = bfr(a0.x) | (bfr(a0.y) << 16);
        o.y = bfr(a0.z) | (bfr(a0.w) << 16);
        o.z = bfr(a1.x) | (bfr(a1.y) << 16);
        o.w = bfr(a1.z) | (bfr(a1.w) << 16);
        xb[i] = o;
        return;
    }
    int tid = blockIdx.x * blockDim.x + threadIdx.x;
    int stride = ABSUM_BLOCKS * 256;
    const float4* w4 = (const float4*)w;
    const int n4 = NELEM_W / 4;
    float s = 0.f;
    for (int i = tid; i < n4; i += stride) {
        float4 v = w4[i];
        s += fabsf(v.x) + fabsf(v.y) + fabsf(v.z) + fabsf(v.w);
    }
    for (int off = 32; off > 0; off >>= 1)
        s += __shfl_down(s, off, 64);
    __shared__ float wsum[4];
    int lane = threadIdx.x & 63;
    int wv   = threadIdx.x >> 6;
    if (lane == 0) wsum[wv] = s;
    __syncthreads();
    if (threadIdx.x == 0)
        apart[blockIdx.x] = wsum[0] + wsum[1] + wsum[2] + wsum[3];   // plain store
}

// ---------------- pass 1.5: reduce 2048 partials -> thr/scale ----------------
__global__ __launch_bounds__(256) void finalize_kernel(const float* __restrict__ apart,
                                                       float* __restrict__ wsf) {
    float s = 0.f;
#pragma unroll
    for (int j = 0; j < 8; ++j)
        s += apart[threadIdx.x + 256 * j];
    for (int off = 32; off > 0; off >>= 1)
        s += __shfl_down(s, off, 64);
    __shared__ float wsum[4];
    int lane = threadIdx.x & 63;
    int wv   = threadIdx.x >> 6;
    if (lane == 0) wsum[wv] = s;
    __syncthreads();
    if (threadIdx.x == 0) {
        double mean = (double)(wsum[0] + wsum[1] + wsum[2] + wsum[3]) / (double)NELEM_W;
        if (mean < 1e-5) mean = 1e-5;
        float mf = (float)mean;
        wsf[2] = 0.7f * mf;   // threshold
        wsf[3] = mf;          // scale
    }
}

// ---------------- ternarize helpers ----------------
__device__ __forceinline__ uint32_t tern1(float v, float thr) {
    uint32_t u  = __float_as_uint(v);
    uint32_t pm = (u & 0x80000000u) | 0x3F800000u;   // +-1.0f
    return (__builtin_fabsf(v) > thr) ? pm : 0u;
}

// 4 fp32 -> 4 ternary bf16 packed in uint2 (v_perm for the pack)
__device__ __forceinline__ uint2 tern4(float4 b, float thr) {
    uint32_t q0 = tern1(b.x, thr), q1 = tern1(b.y, thr);
    uint32_t q2 = tern1(b.z, thr), q3 = tern1(b.w, thr);
    uint2 r;
    r.x = __builtin_amdgcn_perm(q1, q0, 0x07060302u);   // lo16=q0.hi16, hi16=q1.hi16
    r.y = __builtin_amdgcn_perm(q3, q2, 0x07060302u);
    return r;
}

// ---------------- pass 2: LDS-staged ternary GEMM, atomic-free ----------------
// Grid: 688 o-groups x 2 K-halves = 1376 blocks of 128 (2 waves) — 2752 waves,
// fully resident (~10.7 waves/CU). Wave wv covers 1024 k in 16 chunks of 64.
// Staging instr j: lane l loads 16 B of row og*16 + 4j + (l>>4) at float
// offset (l&15)*4 — 16 fully-used 64B lines per instruction.
// 2-deep register double-buffer of w and x. Partials -> d_ws (plain stores).
#define CHUNKS 16
#define WAVE_LDS 2304          // 16 rows * 144 B
#define SMEM_BYTES 4608        // 2 waves; also covers 2*512*4 reduce buf

__global__ __launch_bounds__(128, 4) void ternary_gemm(const float* __restrict__ w,
                                                       const float* __restrict__ wsf,
                                                       const __bf16* __restrict__ xb,
                                                       float* __restrict__ gpart) {
    __shared__ char smem_raw[SMEM_BYTES];
    const float thr = wsf[2];
    const int og   = blockIdx.x >> 1;
    const int kh   = blockIdx.x & 1;
    const int tid  = threadIdx.x;
    const int wv   = tid >> 6;
    const int lane = tid & 63;
    const int col  = lane & 15;     // fragment: output col in group / token
    const int quad = lane >> 4;     // fragment k sub-block; staging row group
    const int rlan = lane & 15;     // staging: 16-B slot within a row

    const int kw = kh * 2048 + wv * 1024;

    const float* wp = w + (size_t)(og * 16 + quad) * IN_F + kw + rlan * 4;
    char* stage = smem_raw + wv * WAVE_LDS;
    char* wr    = stage + quad * 144 + rlan * 8;   // + j*576 per staging instr
    const char* rd = stage + col * 144;
    const __bf16* xq = xb + (size_t)col * IN_F + kw + quad * 8;

    f32x4 acc0 = {0.f, 0.f, 0.f, 0.f};
    f32x4 acc1 = {0.f, 0.f, 0.f, 0.f};

    float4 wb[2][4];
    bf16x8 xv[2][4];

#pragma unroll
    for (int c = 0; c < 2; ++c) {
        const float*  np = wp + c * 64;
        const __bf16* xn = xq + c * 64;
        wb[c][0] = *(const float4*)(np);
        wb[c][1] = *(const float4*)(np + 4 * IN_F);
        wb[c][2] = *(const float4*)(np + 8 * IN_F);
        wb[c][3] = *(const float4*)(np + 12 * IN_F);
        xv[c][0] = *(const bf16x8*)(xn);
        xv[c][1] = *(const bf16x8*)(xn + 32);
        xv[c][2] = *(const bf16x8*)(xn + 16 * IN_F);
        xv[c][3] = *(const bf16x8*)(xn + 16 * IN_F + 32);
    }

#define GEMM_BODY(c, cur)                                                      \
    {                                                                          \
        uint2 t0 = tern4(wb[cur][0], thr);                                     \
        uint2 t1 = tern4(wb[cur][1], thr);                                     \
        uint2 t2 = tern4(wb[cur][2], thr);                                     \
        uint2 t3 = tern4(wb[cur][3], thr);                                     \
        *(uint2*)(wr)        = t0;                                             \
        *(uint2*)(wr + 576)  = t1;                                             \
        *(uint2*)(wr + 1152) = t2;                                             \
        *(uint2*)(wr + 1728) = t3;                                             \
        bf16x8 a00 = xv[cur][0], a01 = xv[cur][1];                             \
        bf16x8 a10 = xv[cur][2], a11 = xv[cur][3];                             \
        if ((c) + 2 < CHUNKS) {                                                \
            const float*  np = wp + ((c) + 2) * 64;                            \
            const __bf16* xn = xq + ((c) + 2) * 64;                            \
            wb[cur][0] = *(const float4*)(np);                                 \
            wb[cur][1] = *(const float4*)(np + 4 * IN_F);                      \
            wb[cur][2] = *(const float4*)(np + 8 * IN_F);                      \
            wb[cur][3] = *(const float4*)(np + 12 * IN_F);                     \
            xv[cur][0] = *(const bf16x8*)(xn);                                 \
            xv[cur][1] = *(const bf16x8*)(xn + 32);                            \
            xv[cur][2] = *(const bf16x8*)(xn + 16 * IN_F);                     \
            xv[cur][3] = *(const bf16x8*)(xn + 16 * IN_F + 32);                \
        }                                                                      \
        bf16x8 bw0 = *(const bf16x8*)(rd + quad * 16);                         \
        bf16x8 bw1 = *(const bf16x8*)(rd + 64 + quad * 16);                    \
        acc0 = __builtin_amdgcn_mfma_f32_16x16x32_bf16(a00, bw0, acc0, 0, 0, 0); \
        acc1 = __builtin_amdgcn_mfma_f32_16x16x32_bf16(a10, bw0, acc1, 0, 0, 0); \
        acc0 = __builtin_amdgcn_mfma_f32_16x16x32_bf16(a01, bw1, acc0, 0, 0, 0); \
        acc1 = __builtin_amdgcn_mfma_f32_16x16x32_bf16(a11, bw1, acc1, 0, 0, 0); \
    }

    for (int c = 0; c < CHUNKS; c += 2) {
        GEMM_BODY(c, 0)
        GEMM_BODY(c + 1, 1)
    }
#undef GEMM_BODY

    __syncthreads();
    float* red  = (float*)smem_raw;
    float* base = red + wv * 512;
#pragma unroll
    for (int r = 0; r < 4; ++r) base[r * 64 + lane]       = acc0[r];
#pragma unroll
    for (int r = 0; r < 4; ++r) base[256 + r * 64 + lane] = acc1[r];
    __syncthreads();

    // 512 outputs (32 tokens x 16 cols), 4 per thread, summed over 2 waves
    float* gp = gpart + (size_t)kh * OUT_ELEMS;
    for (int p = tid; p < 512; p += 128) {
        int t = p >> 4, cc = p & 15;
        int a = t >> 4;
        int q = (t >> 2) & 3;
        int r = t & 3;
        int idx = a * 256 + r * 64 + q * 16 + cc;
        gp[(size_t)t * OUT_F + og * 16 + cc] = red[idx] + red[512 + idx];
    }
}

// ---------------- pass 3: combine split-K partials ----------------
__global__ __launch_bounds__(256) void combine_kernel(const float* __restrict__ gpart,
                                                      const float* __restrict__ wsf,
                                                      float* __restrict__ out) {
    const float sc = wsf[3];
    int i = blockIdx.x * 256 + threadIdx.x;   // float4 index, 88064 total
    const float4* p0 = (const float4*)gpart;
    const float4* p1 = (const float4*)(gpart + OUT_ELEMS);
    float4 a = p0[i], b = p1[i];
    float4 o;
    o.x = (a.x + b.x) * sc;
    o.y = (a.y + b.y) * sc;
    o.z = (a.z + b.z) * sc;
    o.w = (a.w + b.w) * sc;
    ((float4*)out)[i] = o;
}

extern "C" void kernel_launch(void* const* d_in, const int* in_sizes, int n_in,
                              void* d_out, int out_size, void* d_ws, size_t ws_size,
                              hipStream_t stream) {
    const float* x = (const float*)d_in[0];   // [32, 4096]
    const float* w = (const float*)d_in[1];   // [11008, 4096]
    float* out     = (float*)d_out;           // [32, 11008]
    char* ws       = (char*)d_ws;

    float* wsf     = (float*)ws;
    uint4* xb      = (uint4*)(ws + XB_OFF);
    float* gpart   = (float*)(ws + GPART_OFF);
    float* apart   = (float*)(ws + APART_OFF);

    absum_xcvt_kernel<<<ABSUM_BLOCKS + XCVT_BLOCKS, 256, 0, stream>>>(w, x, apart, xb);
    finalize_kernel<<<1, 256, 0, stream>>>(apart, wsf);
    ternary_gemm<<<(OUT_F / 16) * 2, 128, 0, stream>>>(w, wsf, (const __bf16*)(ws + XB_OFF), gpart);
    combine_kernel<<<OUT_ELEMS / 4 / 256, 256, 0, stream>>>(gpart, wsf, out);
}